// Round 8
// baseline (253.886 us; speedup 1.0000x reference)
//
#include <hip/hip_runtime.h>
#include <math.h>

#define CAT    134
#define NRBF   6
#define ADIM   42
#define NBIL   8
#define KPAD   144      // 9 k-steps of 16 (k=134 is the bias column)
#define CHPAD  160      // 5 waves x 32 channels
#define MSTRF  138      // m LDS row stride in FLOATS: 552 B -> 2-way-max bank aliasing
#define TSTR   168      // mae row stride (shorts): 336 B, 16B-aligned rows
#define TE     32       // edges per tile
#define M2     (TE * 67)   // float2 count of one m tile (32*134/2)

typedef __bf16 bf16x8 __attribute__((ext_vector_type(8)));
typedef float  f32x16 __attribute__((ext_vector_type(16)));
typedef float  f32x4  __attribute__((ext_vector_type(4)));

__device__ __forceinline__ unsigned short f32_bf16_rne(float x) {
    union { float f; unsigned u; } v; v.f = x;
    unsigned u = v.u;
    u += 0x7FFFu + ((u >> 16) & 1u);
    return (unsigned short)(u >> 16);
}
__device__ __forceinline__ float bf16_f32(unsigned short h) {
    union { float f; unsigned u; } v; v.u = ((unsigned)h) << 16;
    return v.f;
}
// trunc split: a = hi + lo, |err| ~ 2^-17 |a|
__device__ __forceinline__ void split_pack(float a, float b, unsigned& ph, unsigned& pl) {
    unsigned ua = __float_as_uint(a), ub = __float_as_uint(b);
    ph = (ua >> 16) | (ub & 0xffff0000u);
    float ra = a - __uint_as_float(ua & 0xffff0000u);
    float rb = b - __uint_as_float(ub & 0xffff0000u);
    pl = (__float_as_uint(ra) >> 16) | (__float_as_uint(rb) & 0xffff0000u);
}
__device__ __forceinline__ bf16x8 upack(unsigned a, unsigned b, unsigned c, unsigned d) {
    union { unsigned u[4]; bf16x8 v; } t;
    t.u[0] = a; t.u[1] = b; t.u[2] = c; t.u[3] = d;
    return t.v;
}

// ---------------------------------------------------------------------------
// prep: pack weights into FRAGMENT-MAJOR layout so in-kernel fragment loads
// are fully coalesced:  WF[((wv*9+ks)*64+lane)*16 + {j | 8+j}] = {hi | lo}
// ---------------------------------------------------------------------------
__global__ __launch_bounds__(256) void prep_kernel(
    const float* __restrict__ Wm, const float* __restrict__ bm,
    const float* __restrict__ We, const float* __restrict__ fw,
    unsigned short* __restrict__ WF, unsigned short* __restrict__ WeF,
    unsigned short* __restrict__ FwF)
{
    int i = blockIdx.x * 256 + threadIdx.x;
    if (i < CHPAD * KPAD) {                                  // W_m (+bias col)
        int c = i / KPAD, k = i - c * KPAD;
        float v = 0.f;
        if (c < CAT) {
            if (k < CAT) v = Wm[c * CAT + k];
            else if (k == CAT) v = bm[c];
        }
        unsigned short h = f32_bf16_rne(v);
        unsigned short l = f32_bf16_rne(v - bf16_f32(h));
        int wv = c >> 5, l31 = c & 31, ks = k >> 4;
        int lane = ((k >> 3) & 1) * 32 + l31, j = k & 7;
        size_t idx = ((size_t)(wv * 9 + ks) * 64 + lane) * 16 + j;
        WF[idx] = h; WF[idx + 8] = l;
    } else if (i < CHPAD * KPAD + CHPAD * 16) {              // W_e (K -> 16)
        int j2 = i - CHPAD * KPAD; int c = j2 >> 4, r = j2 & 15;
        float v = (c < CAT && r < NRBF) ? We[c * NRBF + r] : 0.f;
        unsigned short h = f32_bf16_rne(v);
        unsigned short l = f32_bf16_rne(v - bf16_f32(h));
        int wv = c >> 5, l31 = c & 31;
        int lane = (r >> 3) * 32 + l31, j = r & 7;
        size_t idx = ((size_t)wv * 64 + lane) * 16 + j;
        WeF[idx] = h; WeF[idx + 8] = l;
    } else if (i < CHPAD * KPAD + CHPAD * 16 + 16 * CHPAD) { // final_w (16 rows)
        int j3 = i - CHPAD * KPAD - CHPAD * 16;
        int r = j3 / CHPAD, c = j3 - r * CHPAD;
        float v = (r < NRBF && c < CAT) ? fw[r * CAT + c] : 0.f;
        unsigned short h = f32_bf16_rne(v);
        unsigned short l = f32_bf16_rne(v - bf16_f32(h));
        int wv = c >> 5, kk = c & 31;
        int lane = (kk >> 3) * 16 + r, j = kk & 7;
        size_t idx = ((size_t)wv * 64 + lane) * 16 + j;
        FwF[idx] = h; FwF[idx + 8] = l;
    }
}

// ---------------------------------------------------------------------------
// angle: s_a = dot(a_sbf[a,:], colsum(W_a)), scatter-add into sum_s[kj]
// ---------------------------------------------------------------------------
__global__ __launch_bounds__(256) void angle_kernel(
    const float* __restrict__ a_sbf, const int* __restrict__ kj_idx,
    const float* __restrict__ W_a, float* __restrict__ sum_s, int A)
{
    __shared__ float wsum[ADIM];
    int tid = threadIdx.x;
    if (tid < ADIM) {
        float s = 0.f;
        #pragma unroll
        for (int b = 0; b < NBIL; ++b) s += W_a[b * ADIM + tid];
        wsum[tid] = s;
    }
    __syncthreads();

    int a = blockIdx.x * 256 + tid;
    if (a >= A) return;

    const float* row = a_sbf + (size_t)a * ADIM;
    float s = 0.f;
    #pragma unroll
    for (int d2 = 0; d2 < ADIM / 2; ++d2) {
        float2 v = *reinterpret_cast<const float2*>(row + d2 * 2);
        s += v.x * wsum[d2 * 2] + v.y * wsum[d2 * 2 + 1];
    }
    atomicAdd(&sum_s[kj_idx[a]], s);
}

// Zero-instruction opaque pin (kept from round 7 — it helped scheduling).
#define PIN_WEIGHTS()                                                          \
    asm volatile("" :                                                         \
        "+v"(wfh[0]), "+v"(wfh[1]), "+v"(wfh[2]), "+v"(wfh[3]), "+v"(wfh[4]), \
        "+v"(wfh[5]), "+v"(wfh[6]), "+v"(wfh[7]), "+v"(wfh[8]),               \
        "+v"(wfl[0]), "+v"(wfl[1]), "+v"(wfl[2]), "+v"(wfl[3]), "+v"(wfl[4]), \
        "+v"(wfl[5]), "+v"(wfl[6]), "+v"(wfl[7]), "+v"(wfl[8]),               \
        "+v"(weh), "+v"(wel), "+v"(fwh), "+v"(fwl))

// ---------------------------------------------------------------------------
// edge: 32-edge tiles, 5 waves, LDS = 39.2 KB -> 4 blocks/CU.
//   m tile staged as FP32 (split on read); e_rbf per-lane direct;
//   projp overlaid into each wave's private mae column block.
//   2 barriers/tile; next tile's loads prefetched under the MFMA phases.
// ---------------------------------------------------------------------------
__global__ __launch_bounds__(320, 3) void edge_kernel(
    const float* __restrict__ m_ji, const float* __restrict__ e_rbf,
    const unsigned short* __restrict__ WF, const unsigned short* __restrict__ WeF,
    const unsigned short* __restrict__ FwF,
    const float* __restrict__ sum_s, float* __restrict__ out, int E, int NT)
{
    __shared__ float mf32[TE * MSTRF + 8];      // 17696 B
    __shared__ unsigned short maeh[TE][TSTR];   // 10752 B (projp overlaid per-wave)
    __shared__ unsigned short mael[TE][TSTR];   // 10752 B  -> 39200 B total

    const int tid = threadIdx.x;
    const int l   = tid & 63;
    const int wv  = __builtin_amdgcn_readfirstlane(tid >> 6);
    const int l31 = l & 31;
    const int hi5 = l >> 5;

    // ---- persistent weight fragments (normal loads + opaque pin) ---------
    bf16x8 wfh[9], wfl[9];
    #pragma unroll
    for (int ks = 0; ks < 9; ++ks) {
        const unsigned short* p = WF + ((size_t)(wv * 9 + ks) * 64 + l) * 16;
        wfh[ks] = *reinterpret_cast<const bf16x8*>(p);
        wfl[ks] = *reinterpret_cast<const bf16x8*>(p + 8);
    }
    const unsigned short* pe = WeF + ((size_t)wv * 64 + l) * 16;
    bf16x8 weh = *reinterpret_cast<const bf16x8*>(pe);
    bf16x8 wel = *reinterpret_cast<const bf16x8*>(pe + 8);
    const unsigned short* pf = FwF + ((size_t)wv * 64 + l) * 16;
    bf16x8 fwh = *reinterpret_cast<const bf16x8*>(pf);
    bf16x8 fwl = *reinterpret_cast<const bf16x8*>(pf + 8);
    PIN_WEIGHTS();

    // ---- one-time LDS init: bias col 134 = 1.0, cols 135..137 = 0 --------
    if (tid < 128) {
        int r = tid >> 2, j = tid & 3;
        mf32[r * MSTRF + 134 + j] = (j == 0) ? 1.f : 0.f;
    }

    // ---- prologue prefetch ------------------------------------------------
    float2 mpre[7];
    float2 er01 = make_float2(0.f, 0.f), er23 = er01, er45 = er01;
    {
        int t0 = blockIdx.x;
        if (t0 < NT) {
            const float2* mb = reinterpret_cast<const float2*>(m_ji + (size_t)t0 * TE * CAT);
            int nv2 = min(TE, E - t0 * TE) * 67;
            #pragma unroll
            for (int i = 0; i < 7; ++i) {
                int f = tid + i * 320;
                mpre[i] = (f < nv2) ? mb[f] : make_float2(0.f, 0.f);
            }
            int e = t0 * TE + l31;
            if (e < E && hi5 == 0) {
                const float* ep = e_rbf + (size_t)e * NRBF;
                er01 = *reinterpret_cast<const float2*>(ep);
                er23 = *reinterpret_cast<const float2*>(ep + 2);
                er45 = *reinterpret_cast<const float2*>(ep + 4);
            }
        }
    }

    for (int t = blockIdx.x; t < NT; t += gridDim.x) {
        const int e0 = t * TE;
        PIN_WEIGHTS();

        // ---- stage m tile (fp32, no conversion) --------------------------
        #pragma unroll
        for (int i = 0; i < 7; ++i) {
            int f = tid + i * 320;
            if (f < M2) {
                int r = f / 67, c = f - r * 67;
                *reinterpret_cast<float2*>(&mf32[r * MSTRF + 2 * c]) = mpre[i];
            }
        }
        // ---- build THIS tile's eb fragments before er regs are clobbered -
        bf16x8 ebh, ebl;
        {
            unsigned h0, h1, h2, q0, q1, q2;
            split_pack(er01.x, er01.y, h0, q0);
            split_pack(er23.x, er23.y, h1, q1);
            split_pack(er45.x, er45.y, h2, q2);
            ebh = upack(h0, h1, h2, 0);
            ebl = upack(q0, q1, q2, 0);
        }
        __syncthreads();   // barrier A: tile staged

        // ---- issue next tile's global loads (ride under MFMA phases) -----
        {
            int tn = t + gridDim.x;
            if (tn < NT) {
                const float2* mb = reinterpret_cast<const float2*>(m_ji + (size_t)tn * TE * CAT);
                int nv2 = min(TE, E - tn * TE) * 67;
                #pragma unroll
                for (int i = 0; i < 7; ++i) {
                    int f = tid + i * 320;
                    mpre[i] = (f < nv2) ? mb[f] : make_float2(0.f, 0.f);
                }
                er01 = make_float2(0.f, 0.f); er23 = er01; er45 = er01;
                int e = tn * TE + l31;
                if (e < E && hi5 == 0) {
                    const float* ep = e_rbf + (size_t)e * NRBF;
                    er01 = *reinterpret_cast<const float2*>(ep);
                    er23 = *reinterpret_cast<const float2*>(ep + 2);
                    er45 = *reinterpret_cast<const float2*>(ep + 4);
                }
            }
        }

        // ---- MFMA1: x = Wm.m (+bias), split-on-read ----------------------
        f32x16 acc  = {0,0,0,0,0,0,0,0,0,0,0,0,0,0,0,0};
        f32x16 acct = {0,0,0,0,0,0,0,0,0,0,0,0,0,0,0,0};
        const float* mr = &mf32[l31 * MSTRF];
        #pragma unroll
        for (int ks = 0; ks < 9; ++ks) {
            const int cb = (ks < 8) ? (ks * 16 + hi5 * 8) : 128;
            float2 q0 = *reinterpret_cast<const float2*>(mr + cb);
            float2 q1 = *reinterpret_cast<const float2*>(mr + cb + 2);
            float2 q2 = *reinterpret_cast<const float2*>(mr + cb + 4);
            float2 q3 = *reinterpret_cast<const float2*>(mr + cb + 6);
            unsigned H[4], L[4];
            split_pack(q0.x, q0.y, H[0], L[0]);
            split_pack(q1.x, q1.y, H[1], L[1]);
            split_pack(q2.x, q2.y, H[2], L[2]);
            split_pack(q3.x, q3.y, H[3], L[3]);
            if (ks == 8) {   // hi5==1 lanes correspond to k=136..143 (all pad)
                #pragma unroll
                for (int j = 0; j < 4; ++j) { H[j] = hi5 ? 0u : H[j]; L[j] = hi5 ? 0u : L[j]; }
            }
            bf16x8 bh = upack(H[0], H[1], H[2], H[3]);
            bf16x8 bl = upack(L[0], L[1], L[2], L[3]);
            acc = __builtin_amdgcn_mfma_f32_32x32x16_bf16(wfh[ks], bh, acc, 0, 0, 0);
            acc = __builtin_amdgcn_mfma_f32_32x32x16_bf16(wfl[ks], bh, acc, 0, 0, 0);
            acc = __builtin_amdgcn_mfma_f32_32x32x16_bf16(wfh[ks], bl, acc, 0, 0, 0);
        }
        // ---- te = We . eb ------------------------------------------------
        acct = __builtin_amdgcn_mfma_f32_32x32x16_bf16(weh, ebh, acct, 0, 0, 0);
        acct = __builtin_amdgcn_mfma_f32_32x32x16_bf16(wel, ebh, acct, 0, 0, 0);
        acct = __builtin_amdgcn_mfma_f32_32x32x16_bf16(weh, ebl, acct, 0, 0, 0);

        // ---- mae = silu(x)*te -> split -> wave-private LDS slice ---------
        #pragma unroll
        for (int q = 0; q < 4; ++q) {
            float mz[4];
            #pragma unroll
            for (int i = 0; i < 4; ++i) {
                float x  = acc[q * 4 + i];
                float sg = x / (1.f + __expf(-x));
                mz[i] = sg * acct[q * 4 + i];
            }
            unsigned h0, h1, q0, q1;
            split_pack(mz[0], mz[1], h0, q0);
            split_pack(mz[2], mz[3], h1, q1);
            const int cq = 32 * wv + 8 * q + 4 * hi5;
            *reinterpret_cast<uint2*>(&maeh[l31][cq]) = make_uint2(h0, h1);
            *reinterpret_cast<uint2*>(&mael[l31][cq]) = make_uint2(q0, q1);
        }

        // ---- MFMA3: wave reads ONLY its own mae slice; projp overlaid ----
        #pragma unroll
        for (int nt = 0; nt < 2; ++nt) {
            f32x4 a3 = {0, 0, 0, 0};
            const int mrw = nt * 16 + (l & 15);
            bf16x8 bh = *reinterpret_cast<const bf16x8*>(&maeh[mrw][32 * wv + (l >> 4) * 8]);
            bf16x8 bl = *reinterpret_cast<const bf16x8*>(&mael[mrw][32 * wv + (l >> 4) * 8]);
            a3 = __builtin_amdgcn_mfma_f32_16x16x32_bf16(fwh, bh, a3, 0, 0, 0);
            a3 = __builtin_amdgcn_mfma_f32_16x16x32_bf16(fwl, bh, a3, 0, 0, 0);
            a3 = __builtin_amdgcn_mfma_f32_16x16x32_bf16(fwh, bl, a3, 0, 0, 0);
            const int g4 = l >> 4, es = nt * 16 + (l & 15);
            // overlay partial proj into this wave's PRIVATE mae column block
            // (rows for nt=1 reads are 16..31; these writes touch rows 0..15
            //  for nt=0 and 16..31 for nt=1 -> no read/write overlap)
            if (g4 == 0) {
                *reinterpret_cast<f32x4*>(&maeh[es][32 * wv]) = a3;          // rows 0-3
            } else if (g4 == 1) {
                *reinterpret_cast<float*>(&maeh[es][32 * wv + 8])  = a3[0];  // row 4
                *reinterpret_cast<float*>(&maeh[es][32 * wv + 10]) = a3[1];  // row 5
            }
        }
        __syncthreads();   // barrier B: overlay complete, m LDS reusable

        // ---- cross-wave reduce + scale + store ---------------------------
        if (tid < 192) {
            const int es = tid / 6, r = tid - es * 6;
            const int eo = e0 + es;
            if (eo < E) {
                float vsum = 0.f;
                #pragma unroll
                for (int w2 = 0; w2 < 5; ++w2)
                    vsum += *reinterpret_cast<const float*>(&maeh[es][32 * w2 + 2 * r]);
                out[(size_t)eo * NRBF + r] = vsum * sum_s[eo];
            }
        }
    }
}

// ---------------------------------------------------------------------------
extern "C" void kernel_launch(void* const* d_in, const int* in_sizes, int n_in,
                              void* d_out, int out_size, void* d_ws, size_t ws_size,
                              hipStream_t stream)
{
    const float* m_ji    = (const float*)d_in[0];
    // d_in[1] nbr_list, d_in[2] angle_list: unused by the reference math
    const float* e_rbf   = (const float*)d_in[3];
    const float* a_sbf   = (const float*)d_in[4];
    const int*   kj_idx  = (const int*)  d_in[5];
    const float* W_m     = (const float*)d_in[6];
    const float* b_m     = (const float*)d_in[7];
    const float* W_e     = (const float*)d_in[8];
    const float* W_a     = (const float*)d_in[9];
    const float* final_w = (const float*)d_in[10];
    float* out = (float*)d_out;

    const int E  = in_sizes[0] / CAT;
    const int A  = in_sizes[5];
    const int NT = (E + TE - 1) / TE;

    // workspace layout
    char* ws = (char*)d_ws;
    float* sum_s = (float*)ws;
    size_t off = ((size_t)E * 4 + 255) & ~(size_t)255;
    unsigned short* WF  = (unsigned short*)(ws + off); off += (size_t)5 * 9 * 64 * 16 * 2;
    unsigned short* WeF = (unsigned short*)(ws + off); off += (size_t)5 * 64 * 16 * 2;
    unsigned short* FwF = (unsigned short*)(ws + off); off += (size_t)5 * 64 * 16 * 2;

    hipMemsetAsync(sum_s, 0, (size_t)E * sizeof(float), stream);

    const int prep_n = CHPAD * KPAD + CHPAD * 16 + 16 * CHPAD;
    prep_kernel<<<(prep_n + 255) / 256, 256, 0, stream>>>(
        W_m, b_m, W_e, final_w, WF, WeF, FwF);
    angle_kernel<<<(A + 255) / 256, 256, 0, stream>>>(a_sbf, kj_idx, W_a, sum_s, A);

    int grid = 1024; if (grid > NT) grid = NT;
    edge_kernel<<<grid, 320, 0, stream>>>(m_ji, e_rbf, WF, WeF, FwF,
                                          sum_s, out, E, NT);
}